// Round 10
// baseline (554.336 us; speedup 1.0000x reference)
//
#include <hip/hip_runtime.h>

// SimpleRecGNN: 6-layer GCN, N=200000 nodes, E=2000000 edges, dims 16->32(x5)->16.
// Graph build: 2-kernel radix (bucketize 8192-edge tiles -> 391 sub-buckets;
// build: per-sub-bucket LDS count/scan/scatter -> contiguous CSR + row_span +
// dinv + DEGREE-SORTED nodeperm via 64-bin counting sort). prenorm stores
// w' = dinv[src]*w. Layers: out = di*(sum w'*h_src + di*h_self) -> @W+b.
// Layer kernels process nodes in nodeperm (degree-sorted) order so the 8
// nodes of a wave have near-equal degree (kills loop divergence), edge loop
// unrolled x8 for gather MLP (latency-bound). In-wave shuffle transform vs W
// in LDS (+bias+ReLU); layer 4 chains x W5. agg(hW*n) == agg(h*n) W.

namespace {

constexpr int kUsers = 100000;
constexpr int kBooks = 100000;
constexpr int kN = kUsers + kBooks;
constexpr int kE = 2000000;
constexpr int BLK = 256;

constexpr int SUBB = 512;                       // dests per sub-bucket
constexpr int NSUB = (kN + SUBB - 1) / SUBB;    // 391
constexpr int CAP2 = 5888;                      // slots/sub-bucket (+10.7 sigma)
constexpr int TILE = 8192;
constexpr int NTILES = (kE + TILE - 1) / TILE;  // 245

__global__ void init_kernel(int* __restrict__ bcur) {
  int gid = blockIdx.x * blockDim.x + threadIdx.x;
  if (gid < NSUB) bcur[gid] = 0;
}

// h16[node] = (type==0 ? user_emb[clip(nid)] : book_emb[clip(nid-U)])
__global__ void embed_kernel(const int* __restrict__ x,
                             const float* __restrict__ uemb,
                             const float* __restrict__ bemb,
                             float* __restrict__ h) {
  int gid = blockIdx.x * blockDim.x + threadIdx.x;  // exact grid kN*4
  int node = gid >> 2;
  int q = gid & 3;
  if (node >= kN) return;
  int2 xv = ((const int2*)x)[node];
  float4 v;
  if (xv.y == 0) {
    int c = min(max(xv.x, 0), kUsers - 1);
    v = ((const float4*)(uemb + (size_t)c * 16))[q];
  } else {
    int c = min(max(xv.x - kUsers, 0), kBooks - 1);
    v = ((const float4*)(bemb + (size_t)c * 16))[q];
  }
  ((float4*)h)[node * 4 + q] = v;
}

// Pass 1: radix-partition edges into 391 sub-bucket runs of AoS records.
__global__ void __launch_bounds__(BLK) bucketize_kernel(
    const int* __restrict__ ei, const float* __restrict__ ew,
    int* __restrict__ bcur, int4* __restrict__ recs) {
  __shared__ int hist[NSUB];
  __shared__ int gcur[NSUB];
  int base = blockIdx.x * TILE;
  int end = min(kE, base + TILE);
  for (int i = threadIdx.x; i < NSUB; i += BLK) hist[i] = 0;
  __syncthreads();
  const int4* col4 = (const int4*)(ei + kE);
  for (int i = base / 4 + threadIdx.x; i < end / 4; i += BLK) {
    int4 c = col4[i];
    atomicAdd(&hist[c.x >> 9], 1);
    atomicAdd(&hist[c.y >> 9], 1);
    atomicAdd(&hist[c.z >> 9], 1);
    atomicAdd(&hist[c.w >> 9], 1);
  }
  __syncthreads();
  for (int i = threadIdx.x; i < NSUB; i += BLK)
    gcur[i] = atomicAdd(&bcur[i], hist[i]);
  __syncthreads();
  for (int i = base + threadIdx.x; i < end; i += BLK) {
    int r = ei[i];
    int c = ei[kE + i];
    float w = ew[i];
    int b = c >> 9;
    int pos = atomicAdd(&gcur[b], 1);
    pos = min(pos, CAP2 - 1);  // statistically unreachable guard
    recs[(size_t)b * CAP2 + pos] = make_int4(r, c, __float_as_int(w), 0);
  }
}

// Pass 2: one block per sub-bucket: build CSR span in LDS, emit contiguous
// CSR records {src, raw_w}, row_span {beg,end}, dinv, degree-sorted nodeperm.
__global__ void __launch_bounds__(BLK) build_kernel(
    const int4* __restrict__ recs, const int* __restrict__ bcur,
    int2* __restrict__ csr, int2* __restrict__ row_span,
    float* __restrict__ dinv, int* __restrict__ nodeperm) {
  __shared__ int cnt[SUBB];
  __shared__ int off[SUBB];
  __shared__ int cur[SUBB];
  __shared__ int tsum[BLK];
  __shared__ int hist2[64];
  __shared__ int2 stage[CAP2];  // 47 KB
  int b = blockIdx.x;
  int lo = b * SUBB;
  int nloc = min(SUBB, kN - lo);
  int n = min(bcur[b], CAP2);
  const int4* rp = recs + (size_t)b * CAP2;
  int t = threadIdx.x;
  for (int i = t; i < SUBB; i += BLK) cnt[i] = 0;
  if (t < 64) hist2[t] = 0;
  __syncthreads();
  for (int i = t; i < n; i += BLK) atomicAdd(&cnt[rp[i].y - lo], 1);
  __syncthreads();
  int a0 = cnt[2 * t], a1 = cnt[2 * t + 1];
  tsum[t] = a0 + a1;
  __syncthreads();
  for (int o = 1; o < BLK; o <<= 1) {
    int v = (t >= o) ? tsum[t - o] : 0;
    __syncthreads();
    tsum[t] += v;
    __syncthreads();
  }
  int tb = (t == 0) ? 0 : tsum[t - 1];
  off[2 * t] = tb;
  off[2 * t + 1] = tb + a0;
  cur[2 * t] = tb;
  cur[2 * t + 1] = tb + a0;
  __syncthreads();
  int padbase = b * CAP2;
  for (int i = t; i < nloc; i += BLK)
    row_span[lo + i] = make_int2(padbase + off[i], padbase + off[i] + cnt[i]);
  for (int i = t; i < n; i += BLK) {
    int4 rec = rp[i];
    int p = atomicAdd(&cur[rec.y - lo], 1);
    stage[p] = make_int2(rec.x, rec.z);
  }
  // degree histogram for counting sort (bins 0..63)
  for (int i = t; i < nloc; i += BLK) atomicAdd(&hist2[min(cnt[i], 63)], 1);
  __syncthreads();
  if (t == 0) {  // exclusive scan of 64 bins (serial, trivial)
    int run = 0;
    for (int j = 0; j < 64; ++j) {
      int v = hist2[j];
      hist2[j] = run;
      run += v;
    }
  }
  __syncthreads();
  // scatter node ids in degree order
  for (int i = t; i < nloc; i += BLK) {
    int r = atomicAdd(&hist2[min(cnt[i], 63)], 1);
    nodeperm[lo + r] = lo + i;
  }
  // deg/dinv per node
  for (int i = t; i < nloc; i += BLK) {
    float s = 1.0f;  // self-loop
    int e1 = off[i] + cnt[i];
    for (int e = off[i]; e < e1; ++e) s += __int_as_float(stage[e].y);
    dinv[lo + i] = rsqrtf(fmaxf(s, 1e-12f));
  }
  for (int i = t; i < n; i += BLK) csr[padbase + i] = stage[i];
}

// Pass 3: csr.w -> dinv[src] * w (sequential stream; dinv table L2-resident)
__global__ void __launch_bounds__(BLK) prenorm_kernel(
    int2* __restrict__ csr, const int* __restrict__ bcur,
    const float* __restrict__ dinv) {
  int b = blockIdx.x;
  int n = min(bcur[b], CAP2);
  int base = b * CAP2;
  for (int i = threadIdx.x; i < n; i += BLK) {
    int2 rec = csr[base + i];
    csr[base + i].y = __float_as_int(dinv[rec.x] * __int_as_float(rec.y));
  }
}

#define FMA4(A, H, W_)                \
  A.x = fmaf(H.x, W_, A.x);           \
  A.y = fmaf(H.y, W_, A.y);           \
  A.z = fmaf(H.z, W_, A.z);           \
  A.w = fmaf(H.w, W_, A.w);

// Fused layer: propagate (gather, LANES lanes/node x float4, unroll x8,
// degree-sorted node order) then in-wave shuffle transform z = agg @ W + b
// (, ReLU)(, chain x W2 32->16).
template <int LANES, int DOUT, bool RELU, bool CHAIN16>
__global__ void __launch_bounds__(BLK) layer_kernel(
    const float* __restrict__ h, float* __restrict__ outp,
    const int2* __restrict__ row_span, const int2* __restrict__ csr,
    const float* __restrict__ dinv, const int* __restrict__ nodeperm,
    const float* __restrict__ W, const float* __restrict__ bias,
    const float* __restrict__ W2) {
  constexpr int DIN = LANES * 4;
  constexpr int OPL = DOUT / LANES;  // outputs per lane
  __shared__ float sW[DIN * DOUT];
  __shared__ float sB[DOUT];
  __shared__ float sW2[CHAIN16 ? 32 * 16 : 1];
  for (int i = threadIdx.x; i < DIN * DOUT; i += BLK) sW[i] = W[i];
  for (int i = threadIdx.x; i < DOUT; i += BLK) sB[i] = bias[i];
  if (CHAIN16)
    for (int i = threadIdx.x; i < 32 * 16; i += BLK) sW2[i] = W2[i];
  __syncthreads();

  int gid = blockIdx.x * BLK + threadIdx.x;  // exact grid kN*LANES
  int grp = gid / LANES;
  int lane = gid % LANES;
  if (grp >= kN) return;
  int node = nodeperm[grp];
  float di = dinv[node];
  const float4* h4 = (const float4*)h;
  float4 hs = h4[node * LANES + lane];
  int2 span = row_span[node];
  // unroll x8 into 4 independent accumulators (8 gathers in flight)
  float4 A0 = make_float4(0.f, 0.f, 0.f, 0.f), A1 = A0, A2 = A0, A3 = A0;
  int e = span.x;
  for (; e + 7 < span.y; e += 8) {
    int2 r0 = csr[e], r1 = csr[e + 1], r2 = csr[e + 2], r3 = csr[e + 3];
    int2 r4 = csr[e + 4], r5 = csr[e + 5], r6 = csr[e + 6], r7 = csr[e + 7];
    float4 h0 = h4[r0.x * LANES + lane];
    float4 h1 = h4[r1.x * LANES + lane];
    float4 h2 = h4[r2.x * LANES + lane];
    float4 h3 = h4[r3.x * LANES + lane];
    float4 h4v = h4[r4.x * LANES + lane];
    float4 h5 = h4[r5.x * LANES + lane];
    float4 h6 = h4[r6.x * LANES + lane];
    float4 h7 = h4[r7.x * LANES + lane];
    FMA4(A0, h0, __int_as_float(r0.y));
    FMA4(A1, h1, __int_as_float(r1.y));
    FMA4(A2, h2, __int_as_float(r2.y));
    FMA4(A3, h3, __int_as_float(r3.y));
    FMA4(A0, h4v, __int_as_float(r4.y));
    FMA4(A1, h5, __int_as_float(r5.y));
    FMA4(A2, h6, __int_as_float(r6.y));
    FMA4(A3, h7, __int_as_float(r7.y));
  }
  for (; e < span.y; ++e) {
    int2 rc = csr[e];
    float w = __int_as_float(rc.y);
    float4 hv = h4[rc.x * LANES + lane];
    FMA4(A0, hv, w);
  }
  // agg = di*(edges + di*self)
  float ax = ((A0.x + A1.x) + (A2.x + A3.x) + hs.x * di) * di;
  float ay = ((A0.y + A1.y) + (A2.y + A3.y) + hs.y * di) * di;
  float az = ((A0.z + A1.z) + (A2.z + A3.z) + hs.z * di) * di;
  float aw = ((A0.w + A1.w) + (A2.w + A3.w) + hs.w * di) * di;

  // transform: full DIN-vector lives across the LANES lanes of this node.
  float o[OPL];
#pragma unroll
  for (int j = 0; j < OPL; ++j) o[j] = sB[lane * OPL + j];
#pragma unroll
  for (int k = 0; k < DIN; ++k) {
    const int c = k & 3;
    float v = (c == 0) ? ax : (c == 1) ? ay : (c == 2) ? az : aw;
    float hk = __shfl(v, k >> 2, LANES);
    const float* wr = &sW[k * DOUT + lane * OPL];
#pragma unroll
    for (int j = 0; j < OPL; ++j) o[j] = fmaf(hk, wr[j], o[j]);
  }
  if (RELU) {
#pragma unroll
    for (int j = 0; j < OPL; ++j) o[j] = fmaxf(o[j], 0.f);
  }
  if (!CHAIN16) {
    float* op = outp + (size_t)node * DOUT + lane * OPL;
#pragma unroll
    for (int j = 0; j < OPL; j += 4)
      *(float4*)(op + j) = make_float4(o[j], o[j + 1], o[j + 2], o[j + 3]);
  } else {
    // second transform 32->16 (LANES==8, OPL==4); out dims [2*lane, 2*lane+2)
    float o2x = 0.f, o2y = 0.f;
#pragma unroll
    for (int k = 0; k < 32; ++k) {
      const int c = k & 3;
      float v = (c == 0) ? o[0] : (c == 1) ? o[1] : (c == 2) ? o[2] : o[3];
      float hk = __shfl(v, k >> 2, 8);
      o2x = fmaf(hk, sW2[k * 16 + lane * 2 + 0], o2x);
      o2y = fmaf(hk, sW2[k * 16 + lane * 2 + 1], o2y);
    }
    *(float2*)(outp + (size_t)node * 16 + lane * 2) = make_float2(o2x, o2y);
  }
}

// final: out = di*(sum w'*h + di*h_self) + b5 (no transform, no relu)
__global__ void __launch_bounds__(BLK) final_prop_kernel(
    const float* __restrict__ h, float* __restrict__ out,
    const int2* __restrict__ row_span, const int2* __restrict__ csr,
    const float* __restrict__ dinv, const int* __restrict__ nodeperm,
    const float* __restrict__ b5) {
  int gid = blockIdx.x * BLK + threadIdx.x;  // exact grid kN*4
  int grp = gid >> 2;
  int q = gid & 3;
  if (grp >= kN) return;
  int node = nodeperm[grp];
  float di = dinv[node];
  const float4* h4 = (const float4*)h;
  float4 hs = h4[node * 4 + q];
  int2 span = row_span[node];
  float4 A0 = make_float4(0.f, 0.f, 0.f, 0.f), A1 = A0, A2 = A0, A3 = A0;
  int e = span.x;
  for (; e + 7 < span.y; e += 8) {
    int2 r0 = csr[e], r1 = csr[e + 1], r2 = csr[e + 2], r3 = csr[e + 3];
    int2 r4 = csr[e + 4], r5 = csr[e + 5], r6 = csr[e + 6], r7 = csr[e + 7];
    float4 h0 = h4[r0.x * 4 + q];
    float4 h1 = h4[r1.x * 4 + q];
    float4 h2 = h4[r2.x * 4 + q];
    float4 h3 = h4[r3.x * 4 + q];
    float4 h4v = h4[r4.x * 4 + q];
    float4 h5 = h4[r5.x * 4 + q];
    float4 h6 = h4[r6.x * 4 + q];
    float4 h7 = h4[r7.x * 4 + q];
    FMA4(A0, h0, __int_as_float(r0.y));
    FMA4(A1, h1, __int_as_float(r1.y));
    FMA4(A2, h2, __int_as_float(r2.y));
    FMA4(A3, h3, __int_as_float(r3.y));
    FMA4(A0, h4v, __int_as_float(r4.y));
    FMA4(A1, h5, __int_as_float(r5.y));
    FMA4(A2, h6, __int_as_float(r6.y));
    FMA4(A3, h7, __int_as_float(r7.y));
  }
  for (; e < span.y; ++e) {
    int2 rc = csr[e];
    float w = __int_as_float(rc.y);
    float4 hv = h4[rc.x * 4 + q];
    FMA4(A0, hv, w);
  }
  float4 b = ((const float4*)b5)[q];
  float4 r;
  r.x = ((A0.x + A1.x) + (A2.x + A3.x) + hs.x * di) * di + b.x;
  r.y = ((A0.y + A1.y) + (A2.y + A3.y) + hs.y * di) * di + b.y;
  r.z = ((A0.z + A1.z) + (A2.z + A3.z) + hs.z * di) * di + b.z;
  r.w = ((A0.w + A1.w) + (A2.w + A3.w) + hs.w * di) * di + b.w;
  ((float4*)out)[node * 4 + q] = r;
}

inline int cdiv(long a, long b) { return (int)((a + b - 1) / b); }

}  // namespace

extern "C" void kernel_launch(void* const* d_in, const int* in_sizes, int n_in,
                              void* d_out, int out_size, void* d_ws,
                              size_t ws_size, hipStream_t stream) {
  const int* x = (const int*)d_in[0];
  const int* ei = (const int*)d_in[1];
  const float* ew = (const float*)d_in[2];
  const float* uemb = (const float*)d_in[3];
  const float* bemb = (const float*)d_in[4];
  const float* W0 = (const float*)d_in[5];
  const float* b0 = (const float*)d_in[6];
  const float* W1 = (const float*)d_in[7];
  const float* b1 = (const float*)d_in[8];
  const float* W2 = (const float*)d_in[9];
  const float* b2 = (const float*)d_in[10];
  const float* W3 = (const float*)d_in[11];
  const float* b3 = (const float*)d_in[12];
  const float* W4 = (const float*)d_in[13];
  const float* b4 = (const float*)d_in[14];
  const float* W5 = (const float*)d_in[15];
  const float* b5 = (const float*)d_in[16];
  float* out = (float*)d_out;

  char* ws = (char*)d_ws;
  size_t off = 0;
  auto walloc = [&](size_t bytes) -> void* {
    void* p = ws + off;
    off += (bytes + 255) & ~size_t(255);
    return p;
  };
  int2* row_span = (int2*)walloc((size_t)kN * 8);
  float* dinv = (float*)walloc((size_t)kN * 4);
  int* nodeperm = (int*)walloc((size_t)kN * 4);
  int* bcur = (int*)walloc((size_t)NSUB * 4);
  int2* csr = (int2*)walloc((size_t)NSUB * CAP2 * 8);  // padded CSR, 18.4 MB
  float* hA = (float*)walloc((size_t)kN * 32 * 4);     // 25.6 MB
  float* hB = (float*)walloc((size_t)kN * 32 * 4);     // 25.6 MB
  // records overlay hA+hB (36.8 MB <= 51.2 MB); dead after build_kernel.
  int4* recs = (int4*)hA;
  float* hE = hA;   // embed h16 (written after build)
  float* hE2 = hB;  // L4 16-dim output
  (void)ws_size;
  (void)in_sizes;
  (void)n_in;
  (void)out_size;

  // --- graph prep ---
  init_kernel<<<cdiv(NSUB, BLK), BLK, 0, stream>>>(bcur);
  bucketize_kernel<<<NTILES, BLK, 0, stream>>>(ei, ew, bcur, recs);
  build_kernel<<<NSUB, BLK, 0, stream>>>(recs, bcur, csr, row_span, dinv,
                                         nodeperm);
  prenorm_kernel<<<NSUB, BLK, 0, stream>>>(csr, bcur, dinv);
  embed_kernel<<<kN * 4 / BLK, BLK, 0, stream>>>(x, uemb, bemb, hE);

  // --- fused layers (L0 hE->hB, L1 hB->hA, L2 hA->hB, L3 hB->hA,
  //     L4 hA->hE2(16, in hB), final hE2->out) ---
  layer_kernel<4, 32, true, false><<<kN * 4 / BLK, BLK, 0, stream>>>(
      hE, hB, row_span, csr, dinv, nodeperm, W0, b0, nullptr);
  layer_kernel<8, 32, true, false><<<kN * 8 / BLK, BLK, 0, stream>>>(
      hB, hA, row_span, csr, dinv, nodeperm, W1, b1, nullptr);
  layer_kernel<8, 32, true, false><<<kN * 8 / BLK, BLK, 0, stream>>>(
      hA, hB, row_span, csr, dinv, nodeperm, W2, b2, nullptr);
  layer_kernel<8, 32, true, false><<<kN * 8 / BLK, BLK, 0, stream>>>(
      hB, hA, row_span, csr, dinv, nodeperm, W3, b3, nullptr);
  layer_kernel<8, 32, true, true><<<kN * 8 / BLK, BLK, 0, stream>>>(
      hA, hE2, row_span, csr, dinv, nodeperm, W4, b4, W5);
  final_prop_kernel<<<kN * 4 / BLK, BLK, 0, stream>>>(hE2, out, row_span, csr,
                                                      dinv, nodeperm, b5);
}

// Round 11
// 498.621 us; speedup vs baseline: 1.1117x; 1.1117x over previous
//
#include <hip/hip_runtime.h>

// SimpleRecGNN: 6-layer GCN, N=200000 nodes, E=2000000 edges, dims 16->32(x5)->16.
// Graph build: 2-kernel radix (bucketize 8192-edge tiles -> 391 sub-buckets;
// build: per-sub-bucket LDS count/scan/scatter -> contiguous CSR + row_span +
// dinv + DEGREE-SORTED nodeperm via 64-bin counting sort). prenorm stores
// w' = dinv[src]*w. Layers: out = di*(sum w'*h_src + di*h_self) -> @W+b.
// Layer kernels process nodes in nodeperm order (8 nodes/wave have near-equal
// degree -> no loop divergence) with a BIJECTIVE BLOCK SWIZZLE
// (b' = b*9973 mod nblocks) so sorted chunks are spread across launch order
// (no heavy-tail imbalance). Edge loop unrolled x8 (gather-latency bound).
// In-wave shuffle transform vs W in LDS (+bias+ReLU); L4 chains x W5.

namespace {

constexpr int kUsers = 100000;
constexpr int kBooks = 100000;
constexpr int kN = kUsers + kBooks;
constexpr int kE = 2000000;
constexpr int BLK = 256;

constexpr int SUBB = 512;                       // dests per sub-bucket
constexpr int NSUB = (kN + SUBB - 1) / SUBB;    // 391
constexpr int CAP2 = 5888;                      // slots/sub-bucket (+10.7 sigma)
constexpr int TILE = 8192;
constexpr int NTILES = (kE + TILE - 1) / TILE;  // 245

__global__ void init_kernel(int* __restrict__ bcur) {
  int gid = blockIdx.x * blockDim.x + threadIdx.x;
  if (gid < NSUB) bcur[gid] = 0;
}

// h16[node] = (type==0 ? user_emb[clip(nid)] : book_emb[clip(nid-U)])
__global__ void embed_kernel(const int* __restrict__ x,
                             const float* __restrict__ uemb,
                             const float* __restrict__ bemb,
                             float* __restrict__ h) {
  int gid = blockIdx.x * blockDim.x + threadIdx.x;  // exact grid kN*4
  int node = gid >> 2;
  int q = gid & 3;
  if (node >= kN) return;
  int2 xv = ((const int2*)x)[node];
  float4 v;
  if (xv.y == 0) {
    int c = min(max(xv.x, 0), kUsers - 1);
    v = ((const float4*)(uemb + (size_t)c * 16))[q];
  } else {
    int c = min(max(xv.x - kUsers, 0), kBooks - 1);
    v = ((const float4*)(bemb + (size_t)c * 16))[q];
  }
  ((float4*)h)[node * 4 + q] = v;
}

// Pass 1: radix-partition edges into 391 sub-bucket runs of AoS records.
__global__ void __launch_bounds__(BLK) bucketize_kernel(
    const int* __restrict__ ei, const float* __restrict__ ew,
    int* __restrict__ bcur, int4* __restrict__ recs) {
  __shared__ int hist[NSUB];
  __shared__ int gcur[NSUB];
  int base = blockIdx.x * TILE;
  int end = min(kE, base + TILE);
  for (int i = threadIdx.x; i < NSUB; i += BLK) hist[i] = 0;
  __syncthreads();
  const int4* col4 = (const int4*)(ei + kE);
  for (int i = base / 4 + threadIdx.x; i < end / 4; i += BLK) {
    int4 c = col4[i];
    atomicAdd(&hist[c.x >> 9], 1);
    atomicAdd(&hist[c.y >> 9], 1);
    atomicAdd(&hist[c.z >> 9], 1);
    atomicAdd(&hist[c.w >> 9], 1);
  }
  __syncthreads();
  for (int i = threadIdx.x; i < NSUB; i += BLK)
    gcur[i] = atomicAdd(&bcur[i], hist[i]);
  __syncthreads();
  for (int i = base + threadIdx.x; i < end; i += BLK) {
    int r = ei[i];
    int c = ei[kE + i];
    float w = ew[i];
    int b = c >> 9;
    int pos = atomicAdd(&gcur[b], 1);
    pos = min(pos, CAP2 - 1);  // statistically unreachable guard
    recs[(size_t)b * CAP2 + pos] = make_int4(r, c, __float_as_int(w), 0);
  }
}

// Pass 2: one block per sub-bucket: build CSR span in LDS, emit contiguous
// CSR records {src, raw_w}, row_span {beg,end}, dinv, degree-sorted nodeperm.
__global__ void __launch_bounds__(BLK) build_kernel(
    const int4* __restrict__ recs, const int* __restrict__ bcur,
    int2* __restrict__ csr, int2* __restrict__ row_span,
    float* __restrict__ dinv, int* __restrict__ nodeperm) {
  __shared__ int cnt[SUBB];
  __shared__ int off[SUBB];
  __shared__ int cur[SUBB];
  __shared__ int tsum[BLK];
  __shared__ int hist2[64];
  __shared__ int2 stage[CAP2];  // 47 KB
  int b = blockIdx.x;
  int lo = b * SUBB;
  int nloc = min(SUBB, kN - lo);
  int n = min(bcur[b], CAP2);
  const int4* rp = recs + (size_t)b * CAP2;
  int t = threadIdx.x;
  for (int i = t; i < SUBB; i += BLK) cnt[i] = 0;
  if (t < 64) hist2[t] = 0;
  __syncthreads();
  for (int i = t; i < n; i += BLK) atomicAdd(&cnt[rp[i].y - lo], 1);
  __syncthreads();
  int a0 = cnt[2 * t], a1 = cnt[2 * t + 1];
  tsum[t] = a0 + a1;
  __syncthreads();
  for (int o = 1; o < BLK; o <<= 1) {
    int v = (t >= o) ? tsum[t - o] : 0;
    __syncthreads();
    tsum[t] += v;
    __syncthreads();
  }
  int tb = (t == 0) ? 0 : tsum[t - 1];
  off[2 * t] = tb;
  off[2 * t + 1] = tb + a0;
  cur[2 * t] = tb;
  cur[2 * t + 1] = tb + a0;
  __syncthreads();
  int padbase = b * CAP2;
  for (int i = t; i < nloc; i += BLK)
    row_span[lo + i] = make_int2(padbase + off[i], padbase + off[i] + cnt[i]);
  for (int i = t; i < n; i += BLK) {
    int4 rec = rp[i];
    int p = atomicAdd(&cur[rec.y - lo], 1);
    stage[p] = make_int2(rec.x, rec.z);
  }
  // degree histogram for counting sort (bins 0..63)
  for (int i = t; i < nloc; i += BLK) atomicAdd(&hist2[min(cnt[i], 63)], 1);
  __syncthreads();
  if (t == 0) {  // exclusive scan of 64 bins
    int run = 0;
    for (int j = 0; j < 64; ++j) {
      int v = hist2[j];
      hist2[j] = run;
      run += v;
    }
  }
  __syncthreads();
  for (int i = t; i < nloc; i += BLK) {
    int r = atomicAdd(&hist2[min(cnt[i], 63)], 1);
    nodeperm[lo + r] = lo + i;
  }
  for (int i = t; i < nloc; i += BLK) {
    float s = 1.0f;  // self-loop
    int e1 = off[i] + cnt[i];
    for (int e = off[i]; e < e1; ++e) s += __int_as_float(stage[e].y);
    dinv[lo + i] = rsqrtf(fmaxf(s, 1e-12f));
  }
  for (int i = t; i < n; i += BLK) csr[padbase + i] = stage[i];
}

// Pass 3: csr.w -> dinv[src] * w (sequential stream; dinv table L2-resident)
__global__ void __launch_bounds__(BLK) prenorm_kernel(
    int2* __restrict__ csr, const int* __restrict__ bcur,
    const float* __restrict__ dinv) {
  int b = blockIdx.x;
  int n = min(bcur[b], CAP2);
  int base = b * CAP2;
  for (int i = threadIdx.x; i < n; i += BLK) {
    int2 rec = csr[base + i];
    csr[base + i].y = __float_as_int(dinv[rec.x] * __int_as_float(rec.y));
  }
}

#define FMA4(A, H, W_)                \
  A.x = fmaf(H.x, W_, A.x);           \
  A.y = fmaf(H.y, W_, A.y);           \
  A.z = fmaf(H.z, W_, A.z);           \
  A.w = fmaf(H.w, W_, A.w);

// bijective launch-order swizzle (9973 prime, coprime with nblocks)
__device__ __forceinline__ int bswz(int b, int nb) {
  return (int)(((long long)b * 9973) % nb);
}

// Fused layer: propagate (gather, LANES lanes/node x float4, unroll x8,
// degree-sorted node order, swizzled block order) then in-wave shuffle
// transform z = agg @ W + b (, ReLU)(, chain x W2 32->16).
template <int LANES, int DOUT, bool RELU, bool CHAIN16>
__global__ void __launch_bounds__(BLK) layer_kernel(
    const float* __restrict__ h, float* __restrict__ outp,
    const int2* __restrict__ row_span, const int2* __restrict__ csr,
    const float* __restrict__ dinv, const int* __restrict__ nodeperm,
    const float* __restrict__ W, const float* __restrict__ bias,
    const float* __restrict__ W2) {
  constexpr int DIN = LANES * 4;
  constexpr int OPL = DOUT / LANES;  // outputs per lane
  __shared__ float sW[DIN * DOUT];
  __shared__ float sB[DOUT];
  __shared__ float sW2[CHAIN16 ? 32 * 16 : 1];
  for (int i = threadIdx.x; i < DIN * DOUT; i += BLK) sW[i] = W[i];
  for (int i = threadIdx.x; i < DOUT; i += BLK) sB[i] = bias[i];
  if (CHAIN16)
    for (int i = threadIdx.x; i < 32 * 16; i += BLK) sW2[i] = W2[i];
  __syncthreads();

  int gid = bswz(blockIdx.x, gridDim.x) * BLK + threadIdx.x;
  int grp = gid / LANES;
  int lane = gid % LANES;
  if (grp >= kN) return;
  int node = nodeperm[grp];
  float di = dinv[node];
  const float4* h4 = (const float4*)h;
  float4 hs = h4[node * LANES + lane];
  int2 span = row_span[node];
  // unroll x8 into 4 independent accumulators (8 gathers in flight)
  float4 A0 = make_float4(0.f, 0.f, 0.f, 0.f), A1 = A0, A2 = A0, A3 = A0;
  int e = span.x;
  for (; e + 7 < span.y; e += 8) {
    int2 r0 = csr[e], r1 = csr[e + 1], r2 = csr[e + 2], r3 = csr[e + 3];
    int2 r4 = csr[e + 4], r5 = csr[e + 5], r6 = csr[e + 6], r7 = csr[e + 7];
    float4 h0 = h4[r0.x * LANES + lane];
    float4 h1 = h4[r1.x * LANES + lane];
    float4 h2 = h4[r2.x * LANES + lane];
    float4 h3 = h4[r3.x * LANES + lane];
    float4 h4v = h4[r4.x * LANES + lane];
    float4 h5 = h4[r5.x * LANES + lane];
    float4 h6 = h4[r6.x * LANES + lane];
    float4 h7 = h4[r7.x * LANES + lane];
    FMA4(A0, h0, __int_as_float(r0.y));
    FMA4(A1, h1, __int_as_float(r1.y));
    FMA4(A2, h2, __int_as_float(r2.y));
    FMA4(A3, h3, __int_as_float(r3.y));
    FMA4(A0, h4v, __int_as_float(r4.y));
    FMA4(A1, h5, __int_as_float(r5.y));
    FMA4(A2, h6, __int_as_float(r6.y));
    FMA4(A3, h7, __int_as_float(r7.y));
  }
  for (; e < span.y; ++e) {
    int2 rc = csr[e];
    float w = __int_as_float(rc.y);
    float4 hv = h4[rc.x * LANES + lane];
    FMA4(A0, hv, w);
  }
  // agg = di*(edges + di*self)
  float ax = ((A0.x + A1.x) + (A2.x + A3.x) + hs.x * di) * di;
  float ay = ((A0.y + A1.y) + (A2.y + A3.y) + hs.y * di) * di;
  float az = ((A0.z + A1.z) + (A2.z + A3.z) + hs.z * di) * di;
  float aw = ((A0.w + A1.w) + (A2.w + A3.w) + hs.w * di) * di;

  // transform: full DIN-vector lives across the LANES lanes of this node.
  float o[OPL];
#pragma unroll
  for (int j = 0; j < OPL; ++j) o[j] = sB[lane * OPL + j];
#pragma unroll
  for (int k = 0; k < DIN; ++k) {
    const int c = k & 3;
    float v = (c == 0) ? ax : (c == 1) ? ay : (c == 2) ? az : aw;
    float hk = __shfl(v, k >> 2, LANES);
    const float* wr = &sW[k * DOUT + lane * OPL];
#pragma unroll
    for (int j = 0; j < OPL; ++j) o[j] = fmaf(hk, wr[j], o[j]);
  }
  if (RELU) {
#pragma unroll
    for (int j = 0; j < OPL; ++j) o[j] = fmaxf(o[j], 0.f);
  }
  if (!CHAIN16) {
    float* op = outp + (size_t)node * DOUT + lane * OPL;
#pragma unroll
    for (int j = 0; j < OPL; j += 4)
      *(float4*)(op + j) = make_float4(o[j], o[j + 1], o[j + 2], o[j + 3]);
  } else {
    // second transform 32->16 (LANES==8, OPL==4); out dims [2*lane, 2*lane+2)
    float o2x = 0.f, o2y = 0.f;
#pragma unroll
    for (int k = 0; k < 32; ++k) {
      const int c = k & 3;
      float v = (c == 0) ? o[0] : (c == 1) ? o[1] : (c == 2) ? o[2] : o[3];
      float hk = __shfl(v, k >> 2, 8);
      o2x = fmaf(hk, sW2[k * 16 + lane * 2 + 0], o2x);
      o2y = fmaf(hk, sW2[k * 16 + lane * 2 + 1], o2y);
    }
    *(float2*)(outp + (size_t)node * 16 + lane * 2) = make_float2(o2x, o2y);
  }
}

// final: out = di*(sum w'*h + di*h_self) + b5 (no transform, no relu)
__global__ void __launch_bounds__(BLK) final_prop_kernel(
    const float* __restrict__ h, float* __restrict__ out,
    const int2* __restrict__ row_span, const int2* __restrict__ csr,
    const float* __restrict__ dinv, const int* __restrict__ nodeperm,
    const float* __restrict__ b5) {
  int gid = bswz(blockIdx.x, gridDim.x) * BLK + threadIdx.x;
  int grp = gid >> 2;
  int q = gid & 3;
  if (grp >= kN) return;
  int node = nodeperm[grp];
  float di = dinv[node];
  const float4* h4 = (const float4*)h;
  float4 hs = h4[node * 4 + q];
  int2 span = row_span[node];
  float4 A0 = make_float4(0.f, 0.f, 0.f, 0.f), A1 = A0, A2 = A0, A3 = A0;
  int e = span.x;
  for (; e + 7 < span.y; e += 8) {
    int2 r0 = csr[e], r1 = csr[e + 1], r2 = csr[e + 2], r3 = csr[e + 3];
    int2 r4 = csr[e + 4], r5 = csr[e + 5], r6 = csr[e + 6], r7 = csr[e + 7];
    float4 h0 = h4[r0.x * 4 + q];
    float4 h1 = h4[r1.x * 4 + q];
    float4 h2 = h4[r2.x * 4 + q];
    float4 h3 = h4[r3.x * 4 + q];
    float4 h4v = h4[r4.x * 4 + q];
    float4 h5 = h4[r5.x * 4 + q];
    float4 h6 = h4[r6.x * 4 + q];
    float4 h7 = h4[r7.x * 4 + q];
    FMA4(A0, h0, __int_as_float(r0.y));
    FMA4(A1, h1, __int_as_float(r1.y));
    FMA4(A2, h2, __int_as_float(r2.y));
    FMA4(A3, h3, __int_as_float(r3.y));
    FMA4(A0, h4v, __int_as_float(r4.y));
    FMA4(A1, h5, __int_as_float(r5.y));
    FMA4(A2, h6, __int_as_float(r6.y));
    FMA4(A3, h7, __int_as_float(r7.y));
  }
  for (; e < span.y; ++e) {
    int2 rc = csr[e];
    float w = __int_as_float(rc.y);
    float4 hv = h4[rc.x * 4 + q];
    FMA4(A0, hv, w);
  }
  float4 b = ((const float4*)b5)[q];
  float4 r;
  r.x = ((A0.x + A1.x) + (A2.x + A3.x) + hs.x * di) * di + b.x;
  r.y = ((A0.y + A1.y) + (A2.y + A3.y) + hs.y * di) * di + b.y;
  r.z = ((A0.z + A1.z) + (A2.z + A3.z) + hs.z * di) * di + b.z;
  r.w = ((A0.w + A1.w) + (A2.w + A3.w) + hs.w * di) * di + b.w;
  ((float4*)out)[node * 4 + q] = r;
}

inline int cdiv(long a, long b) { return (int)((a + b - 1) / b); }

}  // namespace

extern "C" void kernel_launch(void* const* d_in, const int* in_sizes, int n_in,
                              void* d_out, int out_size, void* d_ws,
                              size_t ws_size, hipStream_t stream) {
  const int* x = (const int*)d_in[0];
  const int* ei = (const int*)d_in[1];
  const float* ew = (const float*)d_in[2];
  const float* uemb = (const float*)d_in[3];
  const float* bemb = (const float*)d_in[4];
  const float* W0 = (const float*)d_in[5];
  const float* b0 = (const float*)d_in[6];
  const float* W1 = (const float*)d_in[7];
  const float* b1 = (const float*)d_in[8];
  const float* W2 = (const float*)d_in[9];
  const float* b2 = (const float*)d_in[10];
  const float* W3 = (const float*)d_in[11];
  const float* b3 = (const float*)d_in[12];
  const float* W4 = (const float*)d_in[13];
  const float* b4 = (const float*)d_in[14];
  const float* W5 = (const float*)d_in[15];
  const float* b5 = (const float*)d_in[16];
  float* out = (float*)d_out;

  char* ws = (char*)d_ws;
  size_t off = 0;
  auto walloc = [&](size_t bytes) -> void* {
    void* p = ws + off;
    off += (bytes + 255) & ~size_t(255);
    return p;
  };
  int2* row_span = (int2*)walloc((size_t)kN * 8);
  float* dinv = (float*)walloc((size_t)kN * 4);
  int* nodeperm = (int*)walloc((size_t)kN * 4);
  int* bcur = (int*)walloc((size_t)NSUB * 4);
  int2* csr = (int2*)walloc((size_t)NSUB * CAP2 * 8);  // padded CSR, 18.4 MB
  float* hA = (float*)walloc((size_t)kN * 32 * 4);     // 25.6 MB
  float* hB = (float*)walloc((size_t)kN * 32 * 4);     // 25.6 MB
  // records overlay hA+hB (36.8 MB <= 51.2 MB); dead after build_kernel.
  int4* recs = (int4*)hA;
  float* hE = hA;   // embed h16 (written after build)
  float* hE2 = hB;  // L4 16-dim output
  (void)ws_size;
  (void)in_sizes;
  (void)n_in;
  (void)out_size;

  // --- graph prep ---
  init_kernel<<<cdiv(NSUB, BLK), BLK, 0, stream>>>(bcur);
  bucketize_kernel<<<NTILES, BLK, 0, stream>>>(ei, ew, bcur, recs);
  build_kernel<<<NSUB, BLK, 0, stream>>>(recs, bcur, csr, row_span, dinv,
                                         nodeperm);
  prenorm_kernel<<<NSUB, BLK, 0, stream>>>(csr, bcur, dinv);
  embed_kernel<<<kN * 4 / BLK, BLK, 0, stream>>>(x, uemb, bemb, hE);

  // --- fused layers (L0 hE->hB, L1 hB->hA, L2 hA->hB, L3 hB->hA,
  //     L4 hA->hE2(16, in hB), final hE2->out) ---
  layer_kernel<4, 32, true, false><<<kN * 4 / BLK, BLK, 0, stream>>>(
      hE, hB, row_span, csr, dinv, nodeperm, W0, b0, nullptr);
  layer_kernel<8, 32, true, false><<<kN * 8 / BLK, BLK, 0, stream>>>(
      hB, hA, row_span, csr, dinv, nodeperm, W1, b1, nullptr);
  layer_kernel<8, 32, true, false><<<kN * 8 / BLK, BLK, 0, stream>>>(
      hA, hB, row_span, csr, dinv, nodeperm, W2, b2, nullptr);
  layer_kernel<8, 32, true, false><<<kN * 8 / BLK, BLK, 0, stream>>>(
      hB, hA, row_span, csr, dinv, nodeperm, W3, b3, nullptr);
  layer_kernel<8, 32, true, true><<<kN * 8 / BLK, BLK, 0, stream>>>(
      hA, hE2, row_span, csr, dinv, nodeperm, W4, b4, W5);
  final_prop_kernel<<<kN * 4 / BLK, BLK, 0, stream>>>(hE2, out, row_span, csr,
                                                      dinv, nodeperm, b5);
}